// Round 2
// baseline (394.257 us; speedup 1.0000x reference)
//
#include <hip/hip_runtime.h>
#include <math.h>

#define B_ 16
#define NSUP_ 4096
#define NQ_ 4096
#define D_ 512
#define C_ 128
#define MARGIN 0.02f   // bf16-split dist err worst ~2e-3; 10x safety

typedef __attribute__((ext_vector_type(8))) short bf16x8;
typedef __attribute__((ext_vector_type(4))) float f32x4;

__device__ inline short f2bf(float f) {   // RNE f32 -> bf16 bits
    unsigned u = __float_as_uint(f);
    unsigned r = (u + 0x7fffu + ((u >> 16) & 1u)) >> 16;
    return (short)r;
}
__device__ inline float bf2f(short h) {
    return __uint_as_float(((unsigned)(unsigned short)h) << 16);
}
__device__ inline void gload16(const void* g, void* l) {
    __builtin_amdgcn_global_load_lds(
        (const __attribute__((address_space(1))) void*)g,
        (__attribute__((address_space(3))) void*)l, 16, 0, 0);
}
__device__ inline void conv8(const float4& fa, const float4& fb, bf16x8& h8, bf16x8& l8) {
    float xv[8] = {fa.x, fa.y, fa.z, fa.w, fb.x, fb.y, fb.z, fb.w};
    #pragma unroll
    for (int e = 0; e < 8; e++) {
        short hb = f2bf(xv[e]);
        h8[e] = hb;
        l8[e] = f2bf(xv[e] - bf2f(hb));
    }
}

// ============ K1: per-batch LDS counting sort (unstable; order-invariance OK) ============
// grid 16, 256 threads. Per-wave histograms (4x less LDS-atomic contention),
// int4-vectorized target loads.
__global__ __launch_bounds__(256) void sort_kernel(
    const int* __restrict__ tgt, int* __restrict__ perm,
    int* __restrict__ class_base, int* __restrict__ class_cnt,
    int* __restrict__ flag_count, int* __restrict__ acc_delta, int* __restrict__ done_ctr)
{
    __shared__ int cnt4[4][C_];
    __shared__ int base[C_];
    int b = blockIdx.x, tid = threadIdx.x;
    int wv = tid >> 6;
    #pragma unroll
    for (int i = tid; i < 4 * C_; i += 256) ((int*)cnt4)[i] = 0;
    __syncthreads();
    const int4* t4 = (const int4*)(tgt + b * NSUP_);
    for (int i = tid; i < NSUP_ / 4; i += 256) {
        int4 v = t4[i];
        atomicAdd(&cnt4[wv][v.x], 1);
        atomicAdd(&cnt4[wv][v.y], 1);
        atomicAdd(&cnt4[wv][v.z], 1);
        atomicAdd(&cnt4[wv][v.w], 1);
    }
    __syncthreads();
    if (tid == 0) {
        int s = 0;
        for (int c = 0; c < C_; c++) {
            int cc = cnt4[0][c] + cnt4[1][c] + cnt4[2][c] + cnt4[3][c];
            base[c] = s;
            class_base[b * C_ + c] = s;
            class_cnt [b * C_ + c] = cc;
            s += cc;
        }
    }
    if (b == 0 && tid == 0) { *flag_count = 0; *acc_delta = 0; *done_ctr = 0; }
    __syncthreads();
    for (int i = tid; i < NSUP_ / 4; i += 256) {
        int4 v = t4[i];
        int i0 = 4 * i;
        int p0 = atomicAdd(&base[v.x], 1); perm[b * NSUP_ + p0] = i0;
        int p1 = atomicAdd(&base[v.y], 1); perm[b * NSUP_ + p1] = i0 + 1;
        int p2 = atomicAdd(&base[v.z], 1); perm[b * NSUP_ + p2] = i0 + 2;
        int p3 = atomicAdd(&base[v.w], 1); perm[b * NSUP_ + p3] = i0 + 3;
    }
}

// ============ K2: gather-reduce prototypes (f64 regs, float4 loads, 2-row MLP) ============
// grid B_*C_ = 2048, 256 threads; half h=tid>>7 handles rows h, h+2, ...;
// thread owns dims (tid&127)*4 .. +3. Also writes pre-split, pre-tiled bf16 A
// (Ahg/Alg) in the exact LDS granule order screen stages with global_load_lds.
__global__ __launch_bounds__(256) void proto_kernel(
    const float* __restrict__ sup, const int* __restrict__ class_base,
    const int* __restrict__ class_cnt, const int* __restrict__ perm,
    short* __restrict__ Ahg, short* __restrict__ Alg,
    double* __restrict__ p64, double* __restrict__ psq64, float* __restrict__ psq32)
{
    __shared__ int rows[256];
    __shared__ double sums[2][512];   // 8 KB
    __shared__ float pm[512];         // f32 means
    __shared__ double red[128];
    int g = blockIdx.x, b = g >> 7, c = g & 127;
    int tid = threadIdx.x;
    int half = tid >> 7, d0 = (tid & 127) * 4;
    int base = class_base[b * C_ + c], cnt = class_cnt[b * C_ + c];
    const float* eb = sup + (size_t)b * NSUP_ * D_;
    double a0 = 0.0, a1 = 0.0, a2 = 0.0, a3 = 0.0;
    double b0 = 0.0, b1 = 0.0, b2 = 0.0, b3 = 0.0;
    for (int r0 = 0; r0 < cnt; r0 += 256) {
        int nr = min(256, cnt - r0);
        __syncthreads();
        if (tid < nr) rows[tid] = perm[b * NSUP_ + base + r0 + tid];
        __syncthreads();
        int r = half;
        for (; r + 2 < nr; r += 4) {   // two rows/iter: 2x loads in flight
            float4 v0 = *(const float4*)(eb + (size_t)rows[r] * D_ + d0);
            float4 v1 = *(const float4*)(eb + (size_t)rows[r + 2] * D_ + d0);
            a0 += (double)v0.x; a1 += (double)v0.y; a2 += (double)v0.z; a3 += (double)v0.w;
            b0 += (double)v1.x; b1 += (double)v1.y; b2 += (double)v1.z; b3 += (double)v1.w;
        }
        if (r < nr) {
            float4 v0 = *(const float4*)(eb + (size_t)rows[r] * D_ + d0);
            a0 += (double)v0.x; a1 += (double)v0.y; a2 += (double)v0.z; a3 += (double)v0.w;
        }
    }
    sums[half][d0 + 0] = a0 + b0; sums[half][d0 + 1] = a1 + b1;
    sums[half][d0 + 2] = a2 + b2; sums[half][d0 + 3] = a3 + b3;
    __syncthreads();
    double cw = (double)(cnt > 1 ? cnt : 1);
    if (tid < 128) {
        double ps = 0.0;
        size_t ob = (size_t)(b * C_ + c) * D_ + d0;
        #pragma unroll
        for (int j = 0; j < 4; j++) {
            double m = (sums[0][d0 + j] + sums[1][d0 + j]) / cw;
            p64[ob + j] = m;
            pm[d0 + j] = (float)m;
            ps += m * m;
        }
        red[tid] = ps;
    }
    __syncthreads();
    for (int s = 64; s > 0; s >>= 1) {
        if (tid < s) red[tid] += red[tid + s];
        __syncthreads();
    }
    if (tid == 0) { psq64[g] = red[0]; psq32[g] = (float)red[0]; }
    // bf16-split tiled granule writes: granule (b, ch, mt, l) with
    // l = ktile*16 + (c&15), covering k = ch*32 + ktile*8 .. +7 of row c.
    if (tid < 64) {
        int ch = tid >> 2, ktile = tid & 3;
        int mt = c >> 4;
        bf16x8 h8, l8;
        #pragma unroll
        for (int e = 0; e < 8; e++) {
            float x = pm[tid * 8 + e];
            short hb = f2bf(x);
            h8[e] = hb;
            l8[e] = f2bf(x - bf2f(hb));
        }
        size_t goff = ((((size_t)b * 16 + ch) * 8 + mt) * 64 + ktile * 16 + (c & 15));
        *(bf16x8*)(Ahg + goff * 8) = h8;
        *(bf16x8*)(Alg + goff * 8) = l8;
    }
}

// ============ K3: MFMA bf16-split screen, 2-deep B prefetch ============
// grid 16 batches x 32 qtiles = 512 blocks, 256 threads (4 waves).
// Block: 128 classes x 128 queries, K=512 in 16 chunks of 32.
// A staged via global_load_lds (L2-resident panel, 1 chunk ahead);
// B reg-prefetched TWO chunks ahead (named reg sets, static indexing),
// conv+ds_write one chunk ahead -> no vmcnt stall at conv.
// Accumulation order identical -> bit-identical output.
__global__ __launch_bounds__(256) void screen_kernel(
    const float* __restrict__ qry, const int* __restrict__ qtgt,
    const short* __restrict__ Ahg, const short* __restrict__ Alg,
    const float* __restrict__ psq32,
    float* __restrict__ out_pred, double* __restrict__ blk_loss,
    float* __restrict__ blk_acc, int* __restrict__ flags, int* __restrict__ flag_count)
{
    __shared__ __align__(16) short Ah[2][4096];   // 8 KB per buf
    __shared__ __align__(16) short Al[2][4096];
    __shared__ __align__(16) short Bh[2][4096];
    __shared__ __align__(16) short Bl[2][4096];
    __shared__ float ldsPsq[C_];
    __shared__ double wl[4];
    __shared__ float  wa[4];

    int blk = blockIdx.x;
    int b   = blk >> 5;
    int qb  = (blk & 31) * 128;
    int tid = threadIdx.x;
    int wave = tid >> 6, lane = tid & 63;
    int quad = lane >> 4, n16 = lane & 15;

    if (tid < C_) ldsPsq[tid] = psq32[b * C_ + tid];

    f32x4 acc[8][2];
    #pragma unroll
    for (int mt = 0; mt < 8; mt++)
        #pragma unroll
        for (int nt = 0; nt < 2; nt++)
            acc[mt][nt] = (f32x4){0.f, 0.f, 0.f, 0.f};

    const float* qbB = qry + ((size_t)b * NQ_ + qb) * D_;
    const short* AhB = Ahg + (size_t)b * 16 * 4096;
    const short* AlB = Alg + (size_t)b * 16 * 4096;

    // This thread's two B granule-pairs: granule G -> q = (G>>6)*16 + (G&15),
    // k-col = ((G>>4)&3)*8. LDS dest byte = G*16 (lane-linear, conflict-free).
    const int G0 = tid, G1 = tid + 256;
    const float* bsrc0 = qbB + (size_t)(((G0 >> 6) << 4) + (G0 & 15)) * D_ + (((G0 >> 4) & 3) << 3);
    const float* bsrc1 = qbB + (size_t)(((G1 >> 6) << 4) + (G1 & 15)) * D_ + (((G1 >> 4) & 3) << 3);

    // two named register sets (static indexing, rule #20)
    float4 eA0, eA1, eA2, eA3;
    float4 eB0, eB1, eB2, eB3;

#define LOADB(SET, CH) { \
        const float* s0_ = bsrc0 + (CH) * 32; \
        const float* s1_ = bsrc1 + (CH) * 32; \
        e##SET##0 = *(const float4*)(s0_); \
        e##SET##1 = *(const float4*)(s0_ + 4); \
        e##SET##2 = *(const float4*)(s1_); \
        e##SET##3 = *(const float4*)(s1_ + 4); }

#define WRITEB(SET, BUF) { \
        bf16x8 h8_, l8_; \
        conv8(e##SET##0, e##SET##1, h8_, l8_); \
        *(bf16x8*)&Bh[BUF][G0 * 8] = h8_; \
        *(bf16x8*)&Bl[BUF][G0 * 8] = l8_; \
        conv8(e##SET##2, e##SET##3, h8_, l8_); \
        *(bf16x8*)&Bh[BUF][G1 * 8] = h8_; \
        *(bf16x8*)&Bl[BUF][G1 * 8] = l8_; }

#define GLOADA(CH, BUF) { \
        const short* sh_ = AhB + (CH) * 4096; \
        const short* sl_ = AlB + (CH) * 4096; \
        char* dh_ = (char*)&Ah[BUF][0]; \
        char* dl_ = (char*)&Al[BUF][0]; \
        gload16(sh_ + tid * 8,        dh_ + tid * 16); \
        gload16(sh_ + 2048 + tid * 8, dh_ + 4096 + tid * 16); \
        gload16(sl_ + tid * 8,        dl_ + tid * 16); \
        gload16(sl_ + 2048 + tid * 8, dl_ + 4096 + tid * 16); }

#define COMPUTE(BUF) { \
        int nt0_ = wave * 2, nt1_ = nt0_ + 1; \
        bf16x8 bh0 = *(const bf16x8*)&Bh[BUF][(nt0_ * 64 + lane) * 8]; \
        bf16x8 bl0 = *(const bf16x8*)&Bl[BUF][(nt0_ * 64 + lane) * 8]; \
        bf16x8 bh1 = *(const bf16x8*)&Bh[BUF][(nt1_ * 64 + lane) * 8]; \
        bf16x8 bl1 = *(const bf16x8*)&Bl[BUF][(nt1_ * 64 + lane) * 8]; \
        _Pragma("unroll") \
        for (int mt = 0; mt < 8; mt++) { \
            bf16x8 ah = *(const bf16x8*)&Ah[BUF][(mt * 64 + lane) * 8]; \
            bf16x8 al = *(const bf16x8*)&Al[BUF][(mt * 64 + lane) * 8]; \
            acc[mt][0] = __builtin_amdgcn_mfma_f32_16x16x32_bf16(ah, bh0, acc[mt][0], 0, 0, 0); \
            acc[mt][0] = __builtin_amdgcn_mfma_f32_16x16x32_bf16(ah, bl0, acc[mt][0], 0, 0, 0); \
            acc[mt][0] = __builtin_amdgcn_mfma_f32_16x16x32_bf16(al, bh0, acc[mt][0], 0, 0, 0); \
            acc[mt][1] = __builtin_amdgcn_mfma_f32_16x16x32_bf16(ah, bh1, acc[mt][1], 0, 0, 0); \
            acc[mt][1] = __builtin_amdgcn_mfma_f32_16x16x32_bf16(ah, bl1, acc[mt][1], 0, 0, 0); \
            acc[mt][1] = __builtin_amdgcn_mfma_f32_16x16x32_bf16(al, bh1, acc[mt][1], 0, 0, 0); \
        } }

    // ---- prologue ----
    LOADB(A, 0);            // B(0) -> set A
    GLOADA(0, 0);           // A(0) -> buf 0
    WRITEB(A, 0);           // B(0) -> buf 0 (waits set-A loads once)
    LOADB(B, 1);            // B(1) -> set B
    __syncthreads();        // drains A(0) gload + B(0) ds_writes (+ set-B loads)

    // ---- main loop: two chunks per iteration, all reg-set indices static ----
    for (int ch = 0; ch < 16; ch += 2) {
        // even chunk: compute buf0 = chunk ch; set B holds B(ch+1)
        if (ch + 2 < 16) LOADB(A, ch + 2);        // B(ch+2) -> set A
        WRITEB(B, 1);                             // B(ch+1) -> buf 1 (regs 1 iter old)
        if (ch + 1 < 16) GLOADA(ch + 1, 1);       // A(ch+1) -> buf 1
        COMPUTE(0);                               // chunk ch
        __syncthreads();
        // odd chunk: compute buf1 = chunk ch+1; set A holds B(ch+2)
        if (ch + 3 < 16) LOADB(B, ch + 3);        // B(ch+3) -> set B
        if (ch + 2 < 16) { WRITEB(A, 0); GLOADA(ch + 2, 0); }
        COMPUTE(1);                               // chunk ch+1
        __syncthreads();
    }

#undef LOADB
#undef WRITEB
#undef GLOADA
#undef COMPUTE

    // ---- epilogue: dist = psq - 2*dot; per-query top2/lse/nll over C/D layout ----
    // C/D: col(query) = lane&15, row(class) = mt*16 + quad*4 + reg
    float4 psqv[8];
    #pragma unroll
    for (int mt = 0; mt < 8; mt++)
        psqv[mt] = *(const float4*)&ldsPsq[mt * 16 + quad * 4];

    double wloss = 0.0; float wacc = 0.0f;

    #pragma unroll
    for (int nt = 0; nt < 2; nt++) {
        int ntg = wave * 2 + nt;
        int qloc = ntg * 16 + n16;
        int gq = b * NQ_ + qb + qloc;
        int tq = qtgt[gq];

        float b1 = 1e30f, b2 = 1e30f, dt = 1e30f, lm = -1e30f;
        int c1 = 0;
        #pragma unroll
        for (int mt = 0; mt < 8; mt++) {
            #pragma unroll
            for (int r = 0; r < 4; r++) {
                float d = psqv[mt][r] - 2.0f * acc[mt][nt][r];
                int c = mt * 16 + quad * 4 + r;
                if (d < b1) { b2 = b1; b1 = d; c1 = c; }
                else if (d < b2) { b2 = d; }
                lm = fmaxf(lm, -d);
                if (c == tq) dt = d;
            }
        }
        float ls = 0.0f;
        #pragma unroll
        for (int mt = 0; mt < 8; mt++) {
            #pragma unroll
            for (int r = 0; r < 4; r++) {
                float d = psqv[mt][r] - 2.0f * acc[mt][nt][r];
                ls += __expf(-d - lm);
            }
        }
        // reduce across the 4 lanes holding this query (xor 16, 32)
        #pragma unroll
        for (int off = 16; off <= 32; off <<= 1) {
            float o1 = __shfl_xor(b1, off, 64);
            int   oc = __shfl_xor(c1, off, 64);
            float o2 = __shfl_xor(b2, off, 64);
            float n2 = fminf(fmaxf(b1, o1), fminf(b2, o2));
            if (o1 < b1 || (o1 == b1 && oc < c1)) { b1 = o1; c1 = oc; }
            b2 = n2;
            float om = __shfl_xor(lm, off, 64);
            float os = __shfl_xor(ls, off, 64);
            float nm = fmaxf(lm, om);
            ls = ls * __expf(lm - nm) + os * __expf(om - nm);
            lm = nm;
            dt = fminf(dt, __shfl_xor(dt, off, 64));
        }
        if (quad == 0) {
            wloss += (double)(dt + lm) + (double)logf(ls);
            wacc  += (c1 == tq) ? 1.0f : 0.0f;
            out_pred[gq] = (float)c1;
            if (b2 - b1 < MARGIN) {
                int pos = atomicAdd(flag_count, 1);
                flags[pos] = gq;
            }
        }
    }

    // wave reduce (contributions live in lanes 0..15 only)
    #pragma unroll
    for (int off = 1; off <= 8; off <<= 1) {
        wloss += __shfl_xor(wloss, off, 64);
        wacc  += __shfl_xor(wacc,  off, 64);
    }
    if (lane == 0) { wl[wave] = wloss; wa[wave] = wacc; }
    __syncthreads();
    if (tid == 0) {
        blk_loss[blk] = wl[0] + wl[1] + wl[2] + wl[3];
        blk_acc[blk]  = wa[0] + wa[1] + wa[2] + wa[3];
    }
}

// ============ K4: exact f64 rescue + fused finalize (ticket) ============
// grid 256, 256 threads; last block to finish runs the final reduction.
__global__ __launch_bounds__(256) void rescue_finalize_kernel(
    const float* __restrict__ qry, const int* __restrict__ qtgt,
    const double* __restrict__ p64, const double* __restrict__ psq64,
    const int* __restrict__ flags, const int* __restrict__ flag_count,
    float* __restrict__ out_pred, int* __restrict__ acc_delta,
    const double* __restrict__ blk_loss, const float* __restrict__ blk_acc,
    int* __restrict__ done_ctr, float* __restrict__ out)
{
    int tid = threadIdx.x, wave = tid >> 6, lane = tid & 63;
    int cnt = *flag_count;
    for (int f = blockIdx.x * 4 + wave; f < cnt; f += 1024) {
        int gq = flags[f];
        int b  = gq >> 12;
        const float* qp = qry + (size_t)gq * D_;
        float4 qa = *(const float4*)(qp + 8 * lane);
        float4 qb4 = *(const float4*)(qp + 8 * lane + 4);
        double q[8] = {(double)qa.x,(double)qa.y,(double)qa.z,(double)qa.w,
                       (double)qb4.x,(double)qb4.y,(double)qb4.z,(double)qb4.w};
        double qsq = 0.0;
        #pragma unroll
        for (int k = 0; k < 8; k++) qsq = fma(q[k], q[k], qsq);
        for (int off = 32; off; off >>= 1) qsq += __shfl_xor(qsq, off, 64);

        const double* pb = p64 + (size_t)b * C_ * D_;
        double bd = 1e300; int bc = 0;
        for (int c = 0; c < C_; c += 2) {
            const double* pr0 = pb + (size_t)c * D_ + 8 * lane;
            const double* pr1 = pr0 + D_;
            double dot0 = 0.0, dot1 = 0.0;
            #pragma unroll
            for (int k = 0; k < 8; k++) {
                dot0 = fma(pr0[k], q[k], dot0);
                dot1 = fma(pr1[k], q[k], dot1);
            }
            for (int off = 32; off; off >>= 1) {
                dot0 += __shfl_xor(dot0, off, 64);
                dot1 += __shfl_xor(dot1, off, 64);
            }
            double d0 = psq64[b * C_ + c]     + qsq - 2.0 * dot0;
            double d1 = psq64[b * C_ + c + 1] + qsq - 2.0 * dot1;
            if (d0 < bd) { bd = d0; bc = c; }
            if (d1 < bd) { bd = d1; bc = c + 1; }
        }
        if (lane == 0) {
            int tq = qtgt[gq];
            int oldc = (int)out_pred[gq];
            if (oldc != bc) {
                out_pred[gq] = (float)bc;
                int delta = ((bc == tq) ? 1 : 0) - ((oldc == tq) ? 1 : 0);
                if (delta) atomicAdd(acc_delta, delta);
            }
        }
    }

    // ---- ticket: last block runs finalize ----
    __shared__ int amlast;
    __syncthreads();
    __threadfence();
    if (tid == 0) amlast = (atomicAdd(done_ctr, 1) == 255) ? 1 : 0;
    __syncthreads();
    if (amlast) {
        __threadfence();
        __shared__ double rl[256];
        __shared__ float  ra[256];
        double s = 0.0; float a = 0.0f;
        for (int i = tid; i < 512; i += 256) { s += blk_loss[i]; a += blk_acc[i]; }
        rl[tid] = s; ra[tid] = a;
        __syncthreads();
        for (int st = 128; st; st >>= 1) {
            if (tid < st) { rl[tid] += rl[tid + st]; ra[tid] += ra[tid + st]; }
            __syncthreads();
        }
        if (tid == 0) {
            out[B_*NQ_    ] = (float)(rl[0] / (double)(B_ * NQ_));
            out[B_*NQ_ + 1] = (ra[0] + (float)(*acc_delta)) / (float)(B_ * NQ_);
        }
    }
}

extern "C" void kernel_launch(void* const* d_in, const int* in_sizes, int n_in,
                              void* d_out, int out_size, void* d_ws, size_t ws_size,
                              hipStream_t stream) {
    const float* sup  = (const float*)d_in[0];
    const float* qry  = (const float*)d_in[1];
    const int*   stgt = (const int*)d_in[2];
    const int*   qtgt = (const int*)d_in[3];
    float* out = (float*)d_out;

    char* ws = (char*)d_ws;
    constexpr size_t O_P64   = 0;                    // 8 MiB
    constexpr size_t O_AH    = O_P64   + 8388608;    // 2 MiB pre-split A high
    constexpr size_t O_AL    = O_AH    + 2097152;    // 2 MiB pre-split A low
    constexpr size_t O_PSQ64 = O_AL    + 2097152;    // 16 KiB
    constexpr size_t O_PSQ32 = O_PSQ64 + 16384;      // 8 KiB
    constexpr size_t O_CBASE = O_PSQ32 + 8192;       // 8 KiB
    constexpr size_t O_CCNT  = O_CBASE + 8192;       // 8 KiB
    constexpr size_t O_PERM  = O_CCNT  + 8192;       // 256 KiB
    constexpr size_t O_BLOSS = O_PERM  + 262144;     // 4 KiB (512 blocks)
    constexpr size_t O_BACC  = O_BLOSS + 4096;       // 2 KiB
    constexpr size_t O_FLAGS = O_BACC  + 2048;       // 256 KiB
    constexpr size_t O_CNT   = O_FLAGS + 262144;

    double* p64       = (double*)(ws + O_P64);
    short*  Ahg       = (short*) (ws + O_AH);
    short*  Alg       = (short*) (ws + O_AL);
    double* psq64     = (double*)(ws + O_PSQ64);
    float*  psq32     = (float*) (ws + O_PSQ32);
    int*    cbase     = (int*)   (ws + O_CBASE);
    int*    ccnt      = (int*)   (ws + O_CCNT);
    int*    perm      = (int*)   (ws + O_PERM);
    double* blk_loss  = (double*)(ws + O_BLOSS);
    float*  blk_acc   = (float*) (ws + O_BACC);
    int*    flags     = (int*)   (ws + O_FLAGS);
    int*    flag_count= (int*)   (ws + O_CNT);
    int*    acc_delta = flag_count + 1;
    int*    done_ctr  = flag_count + 2;

    hipLaunchKernelGGL(sort_kernel,   dim3(16),   dim3(256), 0, stream,
                       stgt, perm, cbase, ccnt, flag_count, acc_delta, done_ctr);
    hipLaunchKernelGGL(proto_kernel,  dim3(2048), dim3(256), 0, stream,
                       sup, cbase, ccnt, perm, Ahg, Alg, p64, psq64, psq32);
    hipLaunchKernelGGL(screen_kernel, dim3(512),  dim3(256), 0, stream,
                       qry, qtgt, Ahg, Alg, psq32, out, blk_loss, blk_acc, flags, flag_count);
    hipLaunchKernelGGL(rescue_finalize_kernel, dim3(256), dim3(256), 0, stream,
                       qry, qtgt, p64, psq64, flags, flag_count, out, acc_delta,
                       blk_loss, blk_acc, done_ctr, out);
}

// Round 3
// 335.710 us; speedup vs baseline: 1.1744x; 1.1744x over previous
//
#include <hip/hip_runtime.h>
#include <math.h>

#define B_ 16
#define NSUP_ 4096
#define NQ_ 4096
#define D_ 512
#define C_ 128
#define MARGIN 0.02f   // bf16-split dist err worst ~2e-3; 10x safety

typedef __attribute__((ext_vector_type(8))) short bf16x8;
typedef __attribute__((ext_vector_type(4))) float f32x4;

__device__ inline short f2bf(float f) {   // RNE f32 -> bf16 bits
    unsigned u = __float_as_uint(f);
    unsigned r = (u + 0x7fffu + ((u >> 16) & 1u)) >> 16;
    return (short)r;
}
__device__ inline float bf2f(short h) {
    return __uint_as_float(((unsigned)(unsigned short)h) << 16);
}
__device__ inline void gload16(const void* g, void* l) {
    __builtin_amdgcn_global_load_lds(
        (const __attribute__((address_space(1))) void*)g,
        (__attribute__((address_space(3))) void*)l, 16, 0, 0);
}
__device__ inline void conv8(const float4& fa, const float4& fb, bf16x8& h8, bf16x8& l8) {
    float xv[8] = {fa.x, fa.y, fa.z, fa.w, fb.x, fb.y, fb.z, fb.w};
    #pragma unroll
    for (int e = 0; e < 8; e++) {
        short hb = f2bf(xv[e]);
        h8[e] = hb;
        l8[e] = f2bf(xv[e] - bf2f(hb));
    }
}

// ============ K1: per-batch LDS counting sort (unstable; order-invariance OK) ============
// grid 16, 256 threads. Per-wave histograms (4x less LDS-atomic contention),
// int4-vectorized target loads.
__global__ __launch_bounds__(256) void sort_kernel(
    const int* __restrict__ tgt, int* __restrict__ perm,
    int* __restrict__ class_base, int* __restrict__ class_cnt,
    int* __restrict__ flag_count, int* __restrict__ acc_delta, int* __restrict__ done_ctr)
{
    __shared__ int cnt4[4][C_];
    __shared__ int base[C_];
    int b = blockIdx.x, tid = threadIdx.x;
    int wv = tid >> 6;
    #pragma unroll
    for (int i = tid; i < 4 * C_; i += 256) ((int*)cnt4)[i] = 0;
    __syncthreads();
    const int4* t4 = (const int4*)(tgt + b * NSUP_);
    for (int i = tid; i < NSUP_ / 4; i += 256) {
        int4 v = t4[i];
        atomicAdd(&cnt4[wv][v.x], 1);
        atomicAdd(&cnt4[wv][v.y], 1);
        atomicAdd(&cnt4[wv][v.z], 1);
        atomicAdd(&cnt4[wv][v.w], 1);
    }
    __syncthreads();
    if (tid == 0) {
        int s = 0;
        for (int c = 0; c < C_; c++) {
            int cc = cnt4[0][c] + cnt4[1][c] + cnt4[2][c] + cnt4[3][c];
            base[c] = s;
            class_base[b * C_ + c] = s;
            class_cnt [b * C_ + c] = cc;
            s += cc;
        }
    }
    if (b == 0 && tid == 0) { *flag_count = 0; *acc_delta = 0; *done_ctr = 0; }
    __syncthreads();
    for (int i = tid; i < NSUP_ / 4; i += 256) {
        int4 v = t4[i];
        int i0 = 4 * i;
        int p0 = atomicAdd(&base[v.x], 1); perm[b * NSUP_ + p0] = i0;
        int p1 = atomicAdd(&base[v.y], 1); perm[b * NSUP_ + p1] = i0 + 1;
        int p2 = atomicAdd(&base[v.z], 1); perm[b * NSUP_ + p2] = i0 + 2;
        int p3 = atomicAdd(&base[v.w], 1); perm[b * NSUP_ + p3] = i0 + 3;
    }
}

// ============ K2: gather-reduce prototypes (f64 regs, float4 loads, 2-row MLP) ============
// grid B_*C_ = 2048, 256 threads; half h=tid>>7 handles rows h, h+2, ...;
// thread owns dims (tid&127)*4 .. +3. Also writes pre-split, pre-tiled bf16 A
// (Ahg/Alg) in the exact LDS granule order screen stages with global_load_lds.
__global__ __launch_bounds__(256) void proto_kernel(
    const float* __restrict__ sup, const int* __restrict__ class_base,
    const int* __restrict__ class_cnt, const int* __restrict__ perm,
    short* __restrict__ Ahg, short* __restrict__ Alg,
    double* __restrict__ p64, double* __restrict__ psq64, float* __restrict__ psq32)
{
    __shared__ int rows[256];
    __shared__ double sums[2][512];   // 8 KB
    __shared__ float pm[512];         // f32 means
    __shared__ double red[128];
    int g = blockIdx.x, b = g >> 7, c = g & 127;
    int tid = threadIdx.x;
    int half = tid >> 7, d0 = (tid & 127) * 4;
    int base = class_base[b * C_ + c], cnt = class_cnt[b * C_ + c];
    const float* eb = sup + (size_t)b * NSUP_ * D_;
    double a0 = 0.0, a1 = 0.0, a2 = 0.0, a3 = 0.0;
    double b0 = 0.0, b1 = 0.0, b2 = 0.0, b3 = 0.0;
    for (int r0 = 0; r0 < cnt; r0 += 256) {
        int nr = min(256, cnt - r0);
        __syncthreads();
        if (tid < nr) rows[tid] = perm[b * NSUP_ + base + r0 + tid];
        __syncthreads();
        int r = half;
        for (; r + 2 < nr; r += 4) {   // two rows/iter: 2x loads in flight
            float4 v0 = *(const float4*)(eb + (size_t)rows[r] * D_ + d0);
            float4 v1 = *(const float4*)(eb + (size_t)rows[r + 2] * D_ + d0);
            a0 += (double)v0.x; a1 += (double)v0.y; a2 += (double)v0.z; a3 += (double)v0.w;
            b0 += (double)v1.x; b1 += (double)v1.y; b2 += (double)v1.z; b3 += (double)v1.w;
        }
        if (r < nr) {
            float4 v0 = *(const float4*)(eb + (size_t)rows[r] * D_ + d0);
            a0 += (double)v0.x; a1 += (double)v0.y; a2 += (double)v0.z; a3 += (double)v0.w;
        }
    }
    sums[half][d0 + 0] = a0 + b0; sums[half][d0 + 1] = a1 + b1;
    sums[half][d0 + 2] = a2 + b2; sums[half][d0 + 3] = a3 + b3;
    __syncthreads();
    double cw = (double)(cnt > 1 ? cnt : 1);
    if (tid < 128) {
        double ps = 0.0;
        size_t ob = (size_t)(b * C_ + c) * D_ + d0;
        #pragma unroll
        for (int j = 0; j < 4; j++) {
            double m = (sums[0][d0 + j] + sums[1][d0 + j]) / cw;
            p64[ob + j] = m;
            pm[d0 + j] = (float)m;
            ps += m * m;
        }
        red[tid] = ps;
    }
    __syncthreads();
    for (int s = 64; s > 0; s >>= 1) {
        if (tid < s) red[tid] += red[tid + s];
        __syncthreads();
    }
    if (tid == 0) { psq64[g] = red[0]; psq32[g] = (float)red[0]; }
    // bf16-split tiled granule writes: granule (b, ch, mt, l) with
    // l = ktile*16 + (c&15), covering k = ch*32 + ktile*8 .. +7 of row c.
    if (tid < 64) {
        int ch = tid >> 2, ktile = tid & 3;
        int mt = c >> 4;
        bf16x8 h8, l8;
        #pragma unroll
        for (int e = 0; e < 8; e++) {
            float x = pm[tid * 8 + e];
            short hb = f2bf(x);
            h8[e] = hb;
            l8[e] = f2bf(x - bf2f(hb));
        }
        size_t goff = ((((size_t)b * 16 + ch) * 8 + mt) * 64 + ktile * 16 + (c & 15));
        *(bf16x8*)(Ahg + goff * 8) = h8;
        *(bf16x8*)(Alg + goff * 8) = l8;
    }
}

// ============ K3: MFMA bf16-split screen, 2-deep B prefetch + candidate masks ============
// grid 16 batches x 32 qtiles = 512 blocks, 256 threads (4 waves).
// Block: 128 classes x 128 queries, K=512 in 16 chunks of 32.
// A staged via global_load_lds (L2-resident panel, 1 chunk ahead);
// B reg-prefetched TWO chunks ahead (named reg sets, static indexing),
// conv+ds_write one chunk ahead -> no vmcnt stall at conv.
// Flag records carry a 128-bit candidate-class mask (d < b1 + MARGIN) so the
// rescue only recomputes ~2 classes instead of all 128.
__global__ __launch_bounds__(256) void screen_kernel(
    const float* __restrict__ qry, const int* __restrict__ qtgt,
    const short* __restrict__ Ahg, const short* __restrict__ Alg,
    const float* __restrict__ psq32,
    float* __restrict__ out_pred, double* __restrict__ blk_loss,
    float* __restrict__ blk_acc, int* __restrict__ flags, int* __restrict__ flag_count)
{
    __shared__ __align__(16) short Ah[2][4096];   // 8 KB per buf
    __shared__ __align__(16) short Al[2][4096];
    __shared__ __align__(16) short Bh[2][4096];
    __shared__ __align__(16) short Bl[2][4096];
    __shared__ float ldsPsq[C_];
    __shared__ double wl[4];
    __shared__ float  wa[4];

    int blk = blockIdx.x;
    int b   = blk >> 5;
    int qb  = (blk & 31) * 128;
    int tid = threadIdx.x;
    int wave = tid >> 6, lane = tid & 63;
    int quad = lane >> 4, n16 = lane & 15;

    if (tid < C_) ldsPsq[tid] = psq32[b * C_ + tid];

    f32x4 acc[8][2];
    #pragma unroll
    for (int mt = 0; mt < 8; mt++)
        #pragma unroll
        for (int nt = 0; nt < 2; nt++)
            acc[mt][nt] = (f32x4){0.f, 0.f, 0.f, 0.f};

    const float* qbB = qry + ((size_t)b * NQ_ + qb) * D_;
    const short* AhB = Ahg + (size_t)b * 16 * 4096;
    const short* AlB = Alg + (size_t)b * 16 * 4096;

    // This thread's two B granule-pairs: granule G -> q = (G>>6)*16 + (G&15),
    // k-col = ((G>>4)&3)*8. LDS dest byte = G*16 (lane-linear, conflict-free).
    const int G0 = tid, G1 = tid + 256;
    const float* bsrc0 = qbB + (size_t)(((G0 >> 6) << 4) + (G0 & 15)) * D_ + (((G0 >> 4) & 3) << 3);
    const float* bsrc1 = qbB + (size_t)(((G1 >> 6) << 4) + (G1 & 15)) * D_ + (((G1 >> 4) & 3) << 3);

    // two named register sets (static indexing, rule #20)
    float4 eA0, eA1, eA2, eA3;
    float4 eB0, eB1, eB2, eB3;

#define LOADB(SET, CH) { \
        const float* s0_ = bsrc0 + (CH) * 32; \
        const float* s1_ = bsrc1 + (CH) * 32; \
        e##SET##0 = *(const float4*)(s0_); \
        e##SET##1 = *(const float4*)(s0_ + 4); \
        e##SET##2 = *(const float4*)(s1_); \
        e##SET##3 = *(const float4*)(s1_ + 4); }

#define WRITEB(SET, BUF) { \
        bf16x8 h8_, l8_; \
        conv8(e##SET##0, e##SET##1, h8_, l8_); \
        *(bf16x8*)&Bh[BUF][G0 * 8] = h8_; \
        *(bf16x8*)&Bl[BUF][G0 * 8] = l8_; \
        conv8(e##SET##2, e##SET##3, h8_, l8_); \
        *(bf16x8*)&Bh[BUF][G1 * 8] = h8_; \
        *(bf16x8*)&Bl[BUF][G1 * 8] = l8_; }

#define GLOADA(CH, BUF) { \
        const short* sh_ = AhB + (CH) * 4096; \
        const short* sl_ = AlB + (CH) * 4096; \
        char* dh_ = (char*)&Ah[BUF][0]; \
        char* dl_ = (char*)&Al[BUF][0]; \
        gload16(sh_ + tid * 8,        dh_ + tid * 16); \
        gload16(sh_ + 2048 + tid * 8, dh_ + 4096 + tid * 16); \
        gload16(sl_ + tid * 8,        dl_ + tid * 16); \
        gload16(sl_ + 2048 + tid * 8, dl_ + 4096 + tid * 16); }

#define COMPUTE(BUF) { \
        int nt0_ = wave * 2, nt1_ = nt0_ + 1; \
        bf16x8 bh0 = *(const bf16x8*)&Bh[BUF][(nt0_ * 64 + lane) * 8]; \
        bf16x8 bl0 = *(const bf16x8*)&Bl[BUF][(nt0_ * 64 + lane) * 8]; \
        bf16x8 bh1 = *(const bf16x8*)&Bh[BUF][(nt1_ * 64 + lane) * 8]; \
        bf16x8 bl1 = *(const bf16x8*)&Bl[BUF][(nt1_ * 64 + lane) * 8]; \
        _Pragma("unroll") \
        for (int mt = 0; mt < 8; mt++) { \
            bf16x8 ah = *(const bf16x8*)&Ah[BUF][(mt * 64 + lane) * 8]; \
            bf16x8 al = *(const bf16x8*)&Al[BUF][(mt * 64 + lane) * 8]; \
            acc[mt][0] = __builtin_amdgcn_mfma_f32_16x16x32_bf16(ah, bh0, acc[mt][0], 0, 0, 0); \
            acc[mt][0] = __builtin_amdgcn_mfma_f32_16x16x32_bf16(ah, bl0, acc[mt][0], 0, 0, 0); \
            acc[mt][0] = __builtin_amdgcn_mfma_f32_16x16x32_bf16(al, bh0, acc[mt][0], 0, 0, 0); \
            acc[mt][1] = __builtin_amdgcn_mfma_f32_16x16x32_bf16(ah, bh1, acc[mt][1], 0, 0, 0); \
            acc[mt][1] = __builtin_amdgcn_mfma_f32_16x16x32_bf16(ah, bl1, acc[mt][1], 0, 0, 0); \
            acc[mt][1] = __builtin_amdgcn_mfma_f32_16x16x32_bf16(al, bh1, acc[mt][1], 0, 0, 0); \
        } }

    // ---- prologue ----
    LOADB(A, 0);            // B(0) -> set A
    GLOADA(0, 0);           // A(0) -> buf 0
    WRITEB(A, 0);           // B(0) -> buf 0 (waits set-A loads once)
    LOADB(B, 1);            // B(1) -> set B
    __syncthreads();        // drains A(0) gload + B(0) ds_writes (+ set-B loads)

    // ---- main loop: two chunks per iteration, all reg-set indices static ----
    for (int ch = 0; ch < 16; ch += 2) {
        // even chunk: compute buf0 = chunk ch; set B holds B(ch+1)
        if (ch + 2 < 16) LOADB(A, ch + 2);        // B(ch+2) -> set A
        WRITEB(B, 1);                             // B(ch+1) -> buf 1 (regs 1 iter old)
        if (ch + 1 < 16) GLOADA(ch + 1, 1);       // A(ch+1) -> buf 1
        COMPUTE(0);                               // chunk ch
        __syncthreads();
        // odd chunk: compute buf1 = chunk ch+1; set A holds B(ch+2)
        if (ch + 3 < 16) LOADB(B, ch + 3);        // B(ch+3) -> set B
        if (ch + 2 < 16) { WRITEB(A, 0); GLOADA(ch + 2, 0); }
        COMPUTE(1);                               // chunk ch+1
        __syncthreads();
    }

#undef LOADB
#undef WRITEB
#undef GLOADA
#undef COMPUTE

    // ---- epilogue: dist = psq - 2*dot; per-query top2/lse/nll over C/D layout ----
    // C/D: col(query) = lane&15, row(class) = mt*16 + quad*4 + reg
    float4 psqv[8];
    #pragma unroll
    for (int mt = 0; mt < 8; mt++)
        psqv[mt] = *(const float4*)&ldsPsq[mt * 16 + quad * 4];

    double wloss = 0.0; float wacc = 0.0f;

    #pragma unroll
    for (int nt = 0; nt < 2; nt++) {
        int ntg = wave * 2 + nt;
        int qloc = ntg * 16 + n16;
        int gq = b * NQ_ + qb + qloc;
        int tq = qtgt[gq];

        float b1 = 1e30f, b2 = 1e30f, dt = 1e30f, lm = -1e30f;
        int c1 = 0;
        #pragma unroll
        for (int mt = 0; mt < 8; mt++) {
            #pragma unroll
            for (int r = 0; r < 4; r++) {
                float d = psqv[mt][r] - 2.0f * acc[mt][nt][r];
                int c = mt * 16 + quad * 4 + r;
                if (d < b1) { b2 = b1; b1 = d; c1 = c; }
                else if (d < b2) { b2 = d; }
                lm = fmaxf(lm, -d);
                if (c == tq) dt = d;
            }
        }
        float ls = 0.0f;
        #pragma unroll
        for (int mt = 0; mt < 8; mt++) {
            #pragma unroll
            for (int r = 0; r < 4; r++) {
                float d = psqv[mt][r] - 2.0f * acc[mt][nt][r];
                ls += __expf(-d - lm);
            }
        }
        // reduce across the 4 lanes holding this query (xor 16, 32)
        #pragma unroll
        for (int off = 16; off <= 32; off <<= 1) {
            float o1 = __shfl_xor(b1, off, 64);
            int   oc = __shfl_xor(c1, off, 64);
            float o2 = __shfl_xor(b2, off, 64);
            float n2 = fminf(fmaxf(b1, o1), fminf(b2, o2));
            if (o1 < b1 || (o1 == b1 && oc < c1)) { b1 = o1; c1 = oc; }
            b2 = n2;
            float om = __shfl_xor(lm, off, 64);
            float os = __shfl_xor(ls, off, 64);
            float nm = fmaxf(lm, om);
            ls = ls * __expf(lm - nm) + os * __expf(om - nm);
            lm = nm;
            dt = fminf(dt, __shfl_xor(dt, off, 64));
        }
        // candidate mask: this lane's 32 classes with d < b1 + MARGIN
        // (b1 is globally reduced; set contains the true argmin by the eps bound)
        unsigned cmask = 0u;
        float thr = b1 + MARGIN;
        #pragma unroll
        for (int mt = 0; mt < 8; mt++) {
            #pragma unroll
            for (int r = 0; r < 4; r++) {
                float d = psqv[mt][r] - 2.0f * acc[mt][nt][r];
                if (d < thr) cmask |= (1u << (mt * 4 + r));
            }
        }
        // gather the 4 quad masks to quad 0 (lane = quad*16 + n16)
        int m1g = __shfl((int)cmask, n16 + 16, 64);
        int m2g = __shfl((int)cmask, n16 + 32, 64);
        int m3g = __shfl((int)cmask, n16 + 48, 64);
        if (quad == 0) {
            wloss += (double)(dt + lm) + (double)logf(ls);
            wacc  += (c1 == tq) ? 1.0f : 0.0f;
            out_pred[gq] = (float)c1;
            if (b2 - b1 < MARGIN) {
                int pos = atomicAdd(flag_count, 1);
                int* fr = flags + pos * 8;
                fr[0] = gq;
                fr[1] = (int)cmask; fr[2] = m1g; fr[3] = m2g; fr[4] = m3g;
            }
        }
    }

    // wave reduce (contributions live in lanes 0..15 only)
    #pragma unroll
    for (int off = 1; off <= 8; off <<= 1) {
        wloss += __shfl_xor(wloss, off, 64);
        wacc  += __shfl_xor(wacc,  off, 64);
    }
    if (lane == 0) { wl[wave] = wloss; wa[wave] = wacc; }
    __syncthreads();
    if (tid == 0) {
        blk_loss[blk] = wl[0] + wl[1] + wl[2] + wl[3];
        blk_acc[blk]  = wa[0] + wa[1] + wa[2] + wa[3];
    }
}

// ============ K4: exact f64 rescue over candidate set + fused finalize (ticket) ============
// grid 256, 256 threads; wave per flag; only candidate classes (typ. 2) recomputed.
// Last block to finish runs the final reduction.
__global__ __launch_bounds__(256) void rescue_finalize_kernel(
    const float* __restrict__ qry, const int* __restrict__ qtgt,
    const double* __restrict__ p64, const double* __restrict__ psq64,
    const int* __restrict__ flags, const int* __restrict__ flag_count,
    float* __restrict__ out_pred, int* __restrict__ acc_delta,
    const double* __restrict__ blk_loss, const float* __restrict__ blk_acc,
    int* __restrict__ done_ctr, float* __restrict__ out)
{
    int tid = threadIdx.x, wave = tid >> 6, lane = tid & 63;
    int cnt = *flag_count;
    for (int f = blockIdx.x * 4 + wave; f < cnt; f += 1024) {
        const int* fr = flags + f * 8;
        int gq = fr[0];
        int b  = gq >> 12;
        const float* qp = qry + (size_t)gq * D_;
        float4 qa = *(const float4*)(qp + 8 * lane);
        float4 qb4 = *(const float4*)(qp + 8 * lane + 4);
        double q[8] = {(double)qa.x,(double)qa.y,(double)qa.z,(double)qa.w,
                       (double)qb4.x,(double)qb4.y,(double)qb4.z,(double)qb4.w};
        double qsq = 0.0;
        #pragma unroll
        for (int k = 0; k < 8; k++) qsq = fma(q[k], q[k], qsq);
        for (int off = 32; off; off >>= 1) qsq += __shfl_xor(qsq, off, 64);

        const double* pb = p64 + (size_t)b * C_ * D_;
        double bd = 1e300; int bc = C_;
        #pragma unroll
        for (int w = 0; w < 4; w++) {
            unsigned m = (unsigned)fr[1 + w];     // wave-uniform -> uniform loop
            while (m) {
                int bit = __ffs((int)m) - 1;
                m &= m - 1u;
                int c = ((bit >> 2) << 4) + (w << 2) + (bit & 3);
                const double* pr = pb + (size_t)c * D_ + 8 * lane;
                double dot = 0.0;
                #pragma unroll
                for (int k = 0; k < 8; k++) dot = fma(pr[k], q[k], dot);
                for (int off = 32; off; off >>= 1) dot += __shfl_xor(dot, off, 64);
                double d = psq64[b * C_ + c] + qsq - 2.0 * dot;
                if (d < bd || (d == bd && c < bc)) { bd = d; bc = c; }
            }
        }
        if (lane == 0) {
            int tq = qtgt[gq];
            int oldc = (int)out_pred[gq];
            if (oldc != bc) {
                out_pred[gq] = (float)bc;
                int delta = ((bc == tq) ? 1 : 0) - ((oldc == tq) ? 1 : 0);
                if (delta) atomicAdd(acc_delta, delta);
            }
        }
    }

    // ---- ticket: last block runs finalize ----
    __shared__ int amlast;
    __syncthreads();
    __threadfence();
    if (tid == 0) amlast = (atomicAdd(done_ctr, 1) == 255) ? 1 : 0;
    __syncthreads();
    if (amlast) {
        __threadfence();
        __shared__ double rl[256];
        __shared__ float  ra[256];
        double s = 0.0; float a = 0.0f;
        for (int i = tid; i < 512; i += 256) { s += blk_loss[i]; a += blk_acc[i]; }
        rl[tid] = s; ra[tid] = a;
        __syncthreads();
        for (int st = 128; st; st >>= 1) {
            if (tid < st) { rl[tid] += rl[tid + st]; ra[tid] += ra[tid + st]; }
            __syncthreads();
        }
        if (tid == 0) {
            out[B_*NQ_    ] = (float)(rl[0] / (double)(B_ * NQ_));
            out[B_*NQ_ + 1] = (ra[0] + (float)(*acc_delta)) / (float)(B_ * NQ_);
        }
    }
}

extern "C" void kernel_launch(void* const* d_in, const int* in_sizes, int n_in,
                              void* d_out, int out_size, void* d_ws, size_t ws_size,
                              hipStream_t stream) {
    const float* sup  = (const float*)d_in[0];
    const float* qry  = (const float*)d_in[1];
    const int*   stgt = (const int*)d_in[2];
    const int*   qtgt = (const int*)d_in[3];
    float* out = (float*)d_out;

    char* ws = (char*)d_ws;
    constexpr size_t O_P64   = 0;                    // 8 MiB
    constexpr size_t O_AH    = O_P64   + 8388608;    // 2 MiB pre-split A high
    constexpr size_t O_AL    = O_AH    + 2097152;    // 2 MiB pre-split A low
    constexpr size_t O_PSQ64 = O_AL    + 2097152;    // 16 KiB
    constexpr size_t O_PSQ32 = O_PSQ64 + 16384;      // 8 KiB
    constexpr size_t O_CBASE = O_PSQ32 + 8192;       // 8 KiB
    constexpr size_t O_CCNT  = O_CBASE + 8192;       // 8 KiB
    constexpr size_t O_PERM  = O_CCNT  + 8192;       // 256 KiB
    constexpr size_t O_BLOSS = O_PERM  + 262144;     // 4 KiB (512 blocks)
    constexpr size_t O_BACC  = O_BLOSS + 4096;       // 2 KiB
    constexpr size_t O_FLAGS = O_BACC  + 2048;       // 2 MiB (65536 flags x 8 ints)
    constexpr size_t O_CNT   = O_FLAGS + 2097152;

    double* p64       = (double*)(ws + O_P64);
    short*  Ahg       = (short*) (ws + O_AH);
    short*  Alg       = (short*) (ws + O_AL);
    double* psq64     = (double*)(ws + O_PSQ64);
    float*  psq32     = (float*) (ws + O_PSQ32);
    int*    cbase     = (int*)   (ws + O_CBASE);
    int*    ccnt      = (int*)   (ws + O_CCNT);
    int*    perm      = (int*)   (ws + O_PERM);
    double* blk_loss  = (double*)(ws + O_BLOSS);
    float*  blk_acc   = (float*) (ws + O_BACC);
    int*    flags     = (int*)   (ws + O_FLAGS);
    int*    flag_count= (int*)   (ws + O_CNT);
    int*    acc_delta = flag_count + 1;
    int*    done_ctr  = flag_count + 2;

    hipLaunchKernelGGL(sort_kernel,   dim3(16),   dim3(256), 0, stream,
                       stgt, perm, cbase, ccnt, flag_count, acc_delta, done_ctr);
    hipLaunchKernelGGL(proto_kernel,  dim3(2048), dim3(256), 0, stream,
                       sup, cbase, ccnt, perm, Ahg, Alg, p64, psq64, psq32);
    hipLaunchKernelGGL(screen_kernel, dim3(512),  dim3(256), 0, stream,
                       qry, qtgt, Ahg, Alg, psq32, out, blk_loss, blk_acc, flags, flag_count);
    hipLaunchKernelGGL(rescue_finalize_kernel, dim3(256), dim3(256), 0, stream,
                       qry, qtgt, p64, psq64, flags, flag_count, out, acc_delta,
                       blk_loss, blk_acc, done_ctr, out);
}